// Round 14
// baseline (120.088 us; speedup 1.0000x reference)
//
#include <hip/hip_runtime.h>
#include <hip/hip_bf16.h>

// y[b,i,j,u] = relu( sum_{c,h} w[u,c,i,h] * x[b,h,j,c] )
// B=16,H=64,W=64,C=64,U=128
// GEMM: M=(b,j)=1024, N=(i,u)=8192, K=(h,c)=4096, kappa=h*64+c.
//
// Pass 1a: Xb[b][h][j][c] = bf16(x)                      (8.39 MB, ws+0)
// Pass 1b: Wb[i][u][h][c] = bf16(w[u][c][i][h])          (64 MB,  ws+8388608)
// Pass 2 : gemm256k -- BM=BN=256, BK=64, SPLIT-K x2 (grid 256 = 4mt x 2ks x
//          32nt2): 32 K-steps/CU instead of 64. Per-step sync cost measured
//          ~constant across r2/r3/r6/r8/r11 (~1800cy floor + work), so
//          halving steps/CU is the one untested lever. 8 waves (2m x 4n,
//          128x64/wave), double-buffered LDS 128KB (stage issued at phase-0
//          start, certified by vmcnt(0) ~2 phases later), r3/r6-proven
//          2-phase barrier skeleton + setprio (T5), (row&7) XOR swizzle
//          (T2), XCD-bijective grid (T1). Partials stored BF16 (error
//          ~0.01 << 0.35 budget) to keep the fix-up pass at 68MB.
// Pass 3 : add_relu_bf: out = relu(f32(P0b) + f32(P1b)).

typedef __attribute__((ext_vector_type(4))) float f32x4;
typedef __attribute__((ext_vector_type(8))) short bf16x8;
typedef __attribute__((ext_vector_type(4))) unsigned int u32x4;
typedef __attribute__((ext_vector_type(2))) unsigned int u32x2;
typedef unsigned short ushort_t;

static __device__ __forceinline__ unsigned int cvt_pk_bf16(float lo, float hi) {
  unsigned int r;
  asm("v_cvt_pk_bf16_f32 %0, %1, %2" : "=v"(r) : "v"(lo), "v"(hi));
  return r;
}

static __device__ __forceinline__ float bf2f(ushort_t u) {
  unsigned int v = ((unsigned int)u) << 16;
  return __builtin_bit_cast(float, v);
}

static __device__ __forceinline__ void async_copy16(void* lds, const void* g) {
  __builtin_amdgcn_global_load_lds(
      (const __attribute__((address_space(1))) unsigned int*)g,
      (__attribute__((address_space(3))) unsigned int*)lds, 16, 0, 0);
}

// ---------------- Pass 1a: x f32 -> bf16 (straight) ----------------
__global__ __launch_bounds__(256)
void conv_x(const float* __restrict__ X, ushort_t* __restrict__ Xb, int n4) {
  int idx = blockIdx.x * 256 + threadIdx.x;
  const int stride = gridDim.x * 256;
  for (; idx < n4; idx += stride) {
    f32x4 v = ((const f32x4*)X)[idx];
    u32x2 o;
    o.x = cvt_pk_bf16(v.x, v.y);
    o.y = cvt_pk_bf16(v.z, v.w);
    ((u32x2*)Xb)[idx] = o;
  }
}

// ---------------- Pass 1b: w[u][c][i][h] -> Wb[i][u][h][c] bf16 ----------------
__global__ __launch_bounds__(256)
void conv_w(const float* __restrict__ W, ushort_t* __restrict__ Wb) {
  __shared__ float T[64][65];  // [c][h], +1 pad
  const int bid = blockIdx.x;       // 8192 blocks = u*64 + i
  const int u = bid >> 6;
  const int i = bid & 63;
  const int t = threadIdx.x;

  const int hq = t & 15;            // 16B chunk of h-row
  const int c4 = t >> 4;            // 0..15
  const float* base = W + (((size_t)u * 64) * 64 + i) * 64;  // + c*4096 + h
#pragma unroll
  for (int it = 0; it < 4; ++it) {
    const int c = it * 16 + c4;
    f32x4 v = *(const f32x4*)(base + (size_t)c * 4096 + hq * 4);
    *(f32x4*)&T[c][hq * 4] = v;
  }
  __syncthreads();

  const int h = t >> 2;
  const int c0 = (t & 3) * 16;
  unsigned int pk[8];
#pragma unroll
  for (int q = 0; q < 8; ++q)
    pk[q] = cvt_pk_bf16(T[c0 + 2 * q][h], T[c0 + 2 * q + 1][h]);
  ushort_t* out = Wb + (((size_t)i * 128 + u) * 64 + h) * 64 + c0;
  ((u32x4*)out)[0] = *(u32x4*)&pk[0];
  ((u32x4*)out)[1] = *(u32x4*)&pk[4];
}

// ---------------- Pass 2: 256x256 BK=64 split-K GEMM, bf16 partials --------
__global__ __launch_bounds__(512, 1)
void gemm256k(const ushort_t* __restrict__ Xb, const ushort_t* __restrict__ Wb,
              ushort_t* __restrict__ P0, ushort_t* __restrict__ P1) {
  __shared__ ushort_t As[2][256 * 64];  // 32KB each, 128B rows, XOR-swizzled
  __shared__ ushort_t Bs[2][256 * 64];  // total 128KB

  const int tid = threadIdx.x;
  const int lane = tid & 63;
  const int wid = tid >> 6;         // 8 waves
  const int wm = wid >> 2;          // 0..1 : 128-row m slab
  const int wn = wid & 3;           // 0..3 : 64-col n slab

  const int bid = blockIdx.x;       // 256 blocks; XCD-bijective swizzle
  const int wg = (bid & 7) * 32 + (bid >> 3);
  const int mt = wg & 3;            // 4 m-tiles of 256
  const int ks = (wg >> 2) & 1;     // k-slice (h-half)
  const int nt2 = wg >> 3;          // 32 n-tiles of 256 (an i-pair)
  const int h0 = ks * 32;           // 32 h-steps per slice

  const char* XbB = (const char*)Xb;
  const char* WbB = (const char*)Wb;

  // ---- staging: LDS dest lane-linear, source carries the (row&7) XOR ----
  int a_dst[4]; size_t a_src[4];
  int b_dst[4]; size_t b_src[4];
#pragma unroll
  for (int it = 0; it < 4; ++it) {
    const int flat = it * 8192 + tid * 16;
    const int row = flat >> 7;            // 0..255
    const int p = (flat >> 4) & 7;
    const int ps = p ^ (row & 7);
    a_dst[it] = flat;
    a_src[it] = (size_t)(mt * 4 + (row >> 6)) * 524288 +
                (size_t)(row & 63) * 128 + ps * 16;      // + h*8192
    b_dst[it] = flat;
    b_src[it] = (size_t)(nt2 * 256 + row) * 8192 + ps * 16;  // + h*128
  }

  // ---- fragment ds_read offsets ----
  int a_ro[2][8], b_ro[2][4];
#pragma unroll
  for (int kk = 0; kk < 2; ++kk) {
#pragma unroll
    for (int f = 0; f < 8; ++f) {
      const int row = wm * 128 + f * 16 + (lane & 15);
      const int byte0 = row * 128 + kk * 64 + (lane >> 4) * 16;
      a_ro[kk][f] = byte0 ^ ((row & 7) << 4);
    }
#pragma unroll
    for (int f = 0; f < 4; ++f) {
      const int row = wn * 64 + f * 16 + (lane & 15);
      const int byte0 = row * 128 + kk * 64 + (lane >> 4) * 16;
      b_ro[kk][f] = byte0 ^ ((row & 7) << 4);
    }
  }

  f32x4 acc[8][4];
#pragma unroll
  for (int i = 0; i < 8; ++i)
#pragma unroll
    for (int j = 0; j < 4; ++j) acc[i][j] = (f32x4){0.f, 0.f, 0.f, 0.f};

  auto stage = [&](int buf, int t) {   // 8 async loads (4 A + 4 B)
    char* la = (char*)&As[buf][0];
    char* lb = (char*)&Bs[buf][0];
    const size_t ha = (size_t)(h0 + t) * 8192;
    const size_t hb = (size_t)(h0 + t) * 128;
#pragma unroll
    for (int it = 0; it < 4; ++it)
      async_copy16(la + a_dst[it], XbB + a_src[it] + ha);
#pragma unroll
    for (int it = 0; it < 4; ++it)
      async_copy16(lb + b_dst[it], WbB + b_src[it] + hb);
  };

  // ---- prologue: stage tile 0 into buf 0; drain ----
  stage(0, 0);
  asm volatile("s_waitcnt vmcnt(0)" ::: "memory");
  __builtin_amdgcn_s_barrier();

  int cur = 0;
  for (int t = 0; t < 32; ++t) {
    const char* ab = (const char*)&As[cur][0];
    const char* bb = (const char*)&Bs[cur][0];
    bf16x8 fa[8], fb[4];

    // ===== phase 0: read kk0 frags, issue stage(t+1) into buf^1, MFMA =====
    __builtin_amdgcn_sched_barrier(0);
#pragma unroll
    for (int f = 0; f < 8; ++f) fa[f] = *(const bf16x8*)(ab + a_ro[0][f]);
#pragma unroll
    for (int f = 0; f < 4; ++f) fb[f] = *(const bf16x8*)(bb + b_ro[0][f]);
    if (t + 1 < 32) stage(cur ^ 1, t + 1);
    __builtin_amdgcn_sched_barrier(0);
    __builtin_amdgcn_s_barrier();
    __builtin_amdgcn_s_setprio(1);
#pragma unroll
    for (int mf = 0; mf < 8; ++mf)
#pragma unroll
      for (int nf = 0; nf < 4; ++nf)
        acc[mf][nf] = __builtin_amdgcn_mfma_f32_16x16x32_bf16(
            fa[mf], fb[nf], acc[mf][nf], 0, 0, 0);
    __builtin_amdgcn_s_setprio(0);
    __builtin_amdgcn_s_barrier();

    // ===== phase 1: read kk1 frags, MFMA, certify t+1, end-of-step bar =====
    __builtin_amdgcn_sched_barrier(0);
#pragma unroll
    for (int f = 0; f < 8; ++f) fa[f] = *(const bf16x8*)(ab + a_ro[1][f]);
#pragma unroll
    for (int f = 0; f < 4; ++f) fb[f] = *(const bf16x8*)(bb + b_ro[1][f]);
    __builtin_amdgcn_sched_barrier(0);
    __builtin_amdgcn_s_barrier();
    __builtin_amdgcn_s_setprio(1);
#pragma unroll
    for (int mf = 0; mf < 8; ++mf)
#pragma unroll
      for (int nf = 0; nf < 4; ++nf)
        acc[mf][nf] = __builtin_amdgcn_mfma_f32_16x16x32_bf16(
            fa[mf], fb[nf], acc[mf][nf], 0, 0, 0);
    __builtin_amdgcn_s_setprio(0);
    // stage(t+1) was issued ~2 phases ago -> drain is cheap; all frag reads
    // of buf[cur] are consumed by the MFMAs above (compiler lgkm waits), so
    // after this barrier buf[cur] may be overwritten at step t+1.
    asm volatile("s_waitcnt vmcnt(0)" ::: "memory");
    __builtin_amdgcn_s_barrier();
    cur ^= 1;
  }

  // ---- epilogue: bf16 partial scatter ----
  ushort_t* P = ks ? P1 : P0;
  const int rbase = (lane >> 4) * 4;
  const int cn = lane & 15;
#pragma unroll
  for (int mf = 0; mf < 8; ++mf) {
#pragma unroll
    for (int r = 0; r < 4; ++r) {
      const int m = mt * 256 + wm * 128 + mf * 16 + rbase + r;
      const int b = m >> 6;
      const int j = m & 63;
#pragma unroll
      for (int nf = 0; nf < 4; ++nf) {
        const int nloc = wn * 64 + nf * 16 + cn;
        const int i = nt2 * 2 + (nloc >> 7);
        const int u = nloc & 127;
        P[(((size_t)b * 64 + i) * 64 + j) * 128 + u] =
            (ushort_t)(cvt_pk_bf16(acc[mf][nf][r], 0.f) & 0xffff);
      }
    }
  }
}

// ---------------- Pass 3: out = relu(f32(P0b) + f32(P1b)) ----------------
__global__ __launch_bounds__(256)
void add_relu_bf(const ushort_t* __restrict__ P0, const ushort_t* __restrict__ P1,
                 float* __restrict__ Out, int n8) {
  const int idx = blockIdx.x * 256 + threadIdx.x;
  if (idx >= n8) return;
  bf16x8 a = ((const bf16x8*)P0)[idx];
  bf16x8 b = ((const bf16x8*)P1)[idx];
  f32x4 o0, o1;
#pragma unroll
  for (int k = 0; k < 4; ++k) {
    o0[k] = fmaxf(bf2f((ushort_t)a[k]) + bf2f((ushort_t)b[k]), 0.f);
    o1[k] = fmaxf(bf2f((ushort_t)a[4 + k]) + bf2f((ushort_t)b[4 + k]), 0.f);
  }
  ((f32x4*)Out)[2 * idx] = o0;
  ((f32x4*)Out)[2 * idx + 1] = o1;
}

// ---------------- Fallback A: round-6 gemm8 (verified 107.0us total) --------
__global__ __launch_bounds__(512, 2)
void gemm8(const ushort_t* __restrict__ Xb, const ushort_t* __restrict__ Wb,
           float* __restrict__ O) {
  __shared__ ushort_t As[3][128 * 64];
  __shared__ ushort_t Bs[3][256 * 64];

  const int tid = threadIdx.x;
  const int lane = tid & 63;
  const int wid = tid >> 6;
  const int wm = wid >> 2;
  const int wn = wid & 3;

  const int bid = blockIdx.x;
  const int wg = (bid & 7) * 32 + (bid >> 3);
  const int mt = wg & 7;
  const int nt2 = wg >> 3;

  const char* XbB = (const char*)Xb;
  const char* WbB = (const char*)Wb;

  int a_dst[2]; size_t a_src[2];
#pragma unroll
  for (int it = 0; it < 2; ++it) {
    const int flat = it * 8192 + tid * 16;
    const int row = flat >> 7;
    const int p = (flat >> 4) & 7;
    const int b = mt * 2 + (row >> 6);
    const int j = row & 63;
    a_dst[it] = flat;
    a_src[it] = (size_t)b * 524288 + (size_t)j * 128 + ((p ^ (row & 7)) << 4);
  }
  int b_dst[4]; size_t b_src[4];
#pragma unroll
  for (int it = 0; it < 4; ++it) {
    const int flat = it * 8192 + tid * 16;
    const int nl = flat >> 7;
    const int p = (flat >> 4) & 7;
    b_dst[it] = flat;
    b_src[it] = (size_t)(nt2 * 256 + nl) * 8192 + ((p ^ (nl & 7)) << 4);
  }

  int a_ro[2][4], b_ro[2][4];
#pragma unroll
  for (int kk = 0; kk < 2; ++kk) {
#pragma unroll
    for (int f = 0; f < 4; ++f) {
      int row = wm * 64 + f * 16 + (lane & 15);
      int byte0 = row * 128 + kk * 64 + (lane >> 4) * 16;
      a_ro[kk][f] = byte0 ^ ((row & 7) << 4);
      row = wn * 64 + f * 16 + (lane & 15);
      byte0 = row * 128 + kk * 64 + (lane >> 4) * 16;
      b_ro[kk][f] = byte0 ^ ((row & 7) << 4);
    }
  }

  f32x4 acc[4][4];
#pragma unroll
  for (int i = 0; i < 4; ++i)
#pragma unroll
    for (int j = 0; j < 4; ++j) acc[i][j] = (f32x4){0.f, 0.f, 0.f, 0.f};

  auto stage = [&](int buf, int h) {
    char* la = (char*)&As[buf][0];
    char* lb = (char*)&Bs[buf][0];
#pragma unroll
    for (int it = 0; it < 2; ++it)
      async_copy16(la + a_dst[it], XbB + a_src[it] + (size_t)h * 8192);
#pragma unroll
    for (int it = 0; it < 4; ++it)
      async_copy16(lb + b_dst[it], WbB + b_src[it] + (size_t)h * 128);
  };
  auto stage3a = [&](int buf, int h) {
    char* la = (char*)&As[buf][0];
    char* lb = (char*)&Bs[buf][0];
#pragma unroll
    for (int it = 0; it < 2; ++it)
      async_copy16(la + a_dst[it], XbB + a_src[it] + (size_t)h * 8192);
    async_copy16(lb + b_dst[0], WbB + b_src[0] + (size_t)h * 128);
  };
  auto stage3b = [&](int buf, int h) {
    char* lb = (char*)&Bs[buf][0];
#pragma unroll
    for (int it = 1; it < 4; ++it)
      async_copy16(lb + b_dst[it], WbB + b_src[it] + (size_t)h * 128);
  };

  bf16x8 fa0[4], fb0[4], fa1[4], fb1[4];
  auto readFrags = [&](bf16x8 (&fa)[4], bf16x8 (&fb)[4], int buf, int kk) {
    const char* ab = (const char*)&As[buf][0];
    const char* bb = (const char*)&Bs[buf][0];
#pragma unroll
    for (int f = 0; f < 4; ++f) fa[f] = *(const bf16x8*)(ab + a_ro[kk][f]);
#pragma unroll
    for (int f = 0; f < 4; ++f) fb[f] = *(const bf16x8*)(bb + b_ro[kk][f]);
  };

  stage(0, 0);
  stage(1, 1);
  asm volatile("s_waitcnt vmcnt(6)" ::: "memory");
  __builtin_amdgcn_s_barrier();
  readFrags(fa0, fb0, 0, 0);

  int cur = 0, nxt = 1, pre = 2;
  for (int t = 0; t < 64; ++t) {
    __builtin_amdgcn_sched_barrier(0);
    readFrags(fa1, fb1, cur, 1);
    if (t + 2 < 64) stage3a(pre, t + 2);
    if (t < 62) {
      asm volatile("s_waitcnt vmcnt(3)" ::: "memory");
    } else {
      asm volatile("s_waitcnt vmcnt(0)" ::: "memory");
    }
    __builtin_amdgcn_sched_barrier(0);
    __builtin_amdgcn_s_barrier();
    __builtin_amdgcn_s_setprio(1);
#pragma unroll
    for (int mf = 0; mf < 4; ++mf)
#pragma unroll
      for (int nf = 0; nf < 4; ++nf)
        acc[mf][nf] = __builtin_amdgcn_mfma_f32_16x16x32_bf16(
            fa0[mf], fb0[nf], acc[mf][nf], 0, 0, 0);
    __builtin_amdgcn_s_setprio(0);
    __builtin_amdgcn_s_barrier();

    __builtin_amdgcn_sched_barrier(0);
    if (t + 1 < 64) readFrags(fa0, fb0, nxt, 0);
    if (t + 2 < 64) stage3b(pre, t + 2);
    __builtin_amdgcn_sched_barrier(0);
    __builtin_amdgcn_s_barrier();
    __builtin_amdgcn_s_setprio(1);
#pragma unroll
    for (int mf = 0; mf < 4; ++mf)
#pragma unroll
      for (int nf = 0; nf < 4; ++nf)
        acc[mf][nf] = __builtin_amdgcn_mfma_f32_16x16x32_bf16(
            fa1[mf], fb1[nf], acc[mf][nf], 0, 0, 0);
    __builtin_amdgcn_s_setprio(0);
    __builtin_amdgcn_s_barrier();

    cur = (cur == 2) ? 0 : cur + 1;
    nxt = (nxt == 2) ? 0 : nxt + 1;
    pre = (pre == 2) ? 0 : pre + 1;
  }

  const int rbase = (lane >> 4) * 4;
  const int cn = lane & 15;
#pragma unroll
  for (int mf = 0; mf < 4; ++mf) {
#pragma unroll
    for (int r = 0; r < 4; ++r) {
      const int ml = wm * 64 + mf * 16 + rbase + r;
      const int m = mt * 128 + ml;
      const int b = m >> 6;
      const int j = m & 63;
#pragma unroll
      for (int nf = 0; nf < 4; ++nf) {
        const int nloc = wn * 64 + nf * 16 + cn;
        const int i = nt2 * 2 + (nloc >> 7);
        const int u = nloc & 127;
        O[(((size_t)b * 64 + i) * 64 + j) * 128 + u] = fmaxf(acc[mf][nf][r], 0.f);
      }
    }
  }
}

// ---------------- Fallback B: round-1 fused kernel (tiny ws) ----------------
__global__ __launch_bounds__(256, 2)
void fused_gemm(const float* __restrict__ X, const float* __restrict__ Wt,
                float* __restrict__ O) {
  __shared__ ushort_t As[2][128 * 64];
  __shared__ ushort_t Bs[2][128 * 64];
  const int tid = threadIdx.x;
  const int lane = tid & 63;
  const int wid = tid >> 6;
  const int wm = wid >> 1;
  const int wn = wid & 1;
  const int bid = blockIdx.x;
  const int wg = (bid & 7) * 64 + (bid >> 3);
  const int mt = wg & 7;
  const int nt = wg >> 3;
  const int a_ml = tid >> 1;
  const int a_hp = (tid & 1) * 2;
  const int a_b = (mt * 128 + a_ml) >> 6;
  const int a_j = a_ml & 63;
  const float* a_base = X + ((size_t)a_b << 18) + ((size_t)a_j << 6);
  const int b_nl = tid >> 1;
  const int b_c8 = (tid & 1) * 8;
  const float* b_base = Wt + ((size_t)b_nl << 18) + ((size_t)nt << 6);
  f32x4 ra[2][4];
  f32x4 rb[8];
  f32x4 acc[4][4];
#pragma unroll
  for (int i = 0; i < 4; ++i)
#pragma unroll
    for (int j = 0; j < 4; ++j) acc[i][j] = (f32x4){0.f, 0.f, 0.f, 0.f};
  auto stage_load = [&](int t) {
    const int th = t & 15;
    const int tc = t >> 4;
    const int c0 = tc * 16;
    const int h0 = th * 4;
#pragma unroll
    for (int s = 0; s < 2; ++s) {
      const float* p = a_base + (size_t)(h0 + a_hp + s) * 4096 + c0;
#pragma unroll
      for (int q = 0; q < 4; ++q) ra[s][q] = ((const f32x4*)p)[q];
    }
#pragma unroll
    for (int q = 0; q < 8; ++q)
      rb[q] = *(const f32x4*)(b_base + (size_t)(c0 + b_c8 + q) * 4096 + h0);
  };
  auto stage_write = [&](int buf) {
    char* abase = (char*)&As[buf][0];
    const int swa = (a_ml & 7) << 4;
#pragma unroll
    for (int s = 0; s < 2; ++s) {
      u32x4 lo, hi;
      lo.x = cvt_pk_bf16(ra[s][0].x, ra[s][0].y);
      lo.y = cvt_pk_bf16(ra[s][0].z, ra[s][0].w);
      lo.z = cvt_pk_bf16(ra[s][1].x, ra[s][1].y);
      lo.w = cvt_pk_bf16(ra[s][1].z, ra[s][1].w);
      hi.x = cvt_pk_bf16(ra[s][2].x, ra[s][2].y);
      hi.y = cvt_pk_bf16(ra[s][2].z, ra[s][2].w);
      hi.z = cvt_pk_bf16(ra[s][3].x, ra[s][3].y);
      hi.w = cvt_pk_bf16(ra[s][3].z, ra[s][3].w);
      const int byte0 = a_ml * 128 + (a_hp + s) * 32;
      *(u32x4*)(abase + (byte0 ^ swa)) = lo;
      *(u32x4*)(abase + ((byte0 + 16) ^ swa)) = hi;
    }
    char* bbase = (char*)&Bs[buf][0];
    const int swb = (b_nl & 7) << 4;
#pragma unroll
    for (int hl = 0; hl < 4; ++hl) {
      u32x4 v;
      v.x = cvt_pk_bf16(rb[0][hl], rb[1][hl]);
      v.y = cvt_pk_bf16(rb[2][hl], rb[3][hl]);
      v.z = cvt_pk_bf16(rb[4][hl], rb[5][hl]);
      v.w = cvt_pk_bf16(rb[6][hl], rb[7][hl]);
      const int byte0 = b_nl * 128 + (hl * 16 + b_c8) * 2;
      *(u32x4*)(bbase + (byte0 ^ swb)) = v;
    }
  };
  auto compute = [&](int buf) {
    const char* abase = (const char*)&As[buf][0];
    const char* bbase = (const char*)&Bs[buf][0];
#pragma unroll
    for (int kk = 0; kk < 2; ++kk) {
      bf16x8 af[4], bfr[4];
#pragma unroll
      for (int mf = 0; mf < 4; ++mf) {
        const int row = wm * 64 + mf * 16 + (lane & 15);
        const int byte0 = row * 128 + kk * 64 + (lane >> 4) * 16;
        af[mf] = *(const bf16x8*)(abase + (byte0 ^ ((row & 7) << 4)));
      }
#pragma unroll
      for (int nf = 0; nf < 4; ++nf) {
        const int row = wn * 64 + nf * 16 + (lane & 15);
        const int byte0 = row * 128 + kk * 64 + (lane >> 4) * 16;
        bfr[nf] = *(const bf16x8*)(bbase + (byte0 ^ ((row & 7) << 4)));
      }
#pragma unroll
      for (int mf = 0; mf < 4; ++mf)
#pragma unroll
        for (int nf = 0; nf < 4; ++nf)
          acc[mf][nf] = __builtin_amdgcn_mfma_f32_16x16x32_bf16(
              af[mf], bfr[nf], acc[mf][nf], 0, 0, 0);
    }
  };
  stage_load(0);
  stage_write(0);
  __syncthreads();
  int cur = 0;
  for (int t = 0; t < 64; ++t) {
    if (t + 1 < 64) stage_load(t + 1);
    compute(cur);
    if (t + 1 < 64) stage_write(cur ^ 1);
    __syncthreads();
    cur ^= 1;
  }
  const int rbase = (lane >> 4) * 4;
  const int cn = lane & 15;
#pragma unroll
  for (int mf = 0; mf < 4; ++mf) {
#pragma unroll
    for (int r = 0; r < 4; ++r) {
      const int ml = wm * 64 + mf * 16 + rbase + r;
      const int m = mt * 128 + ml;
      const int b = m >> 6;
      const int j = m & 63;
      float* orow = O + (((size_t)b * 64 + nt) * 64 + j) * 128;
#pragma unroll
      for (int nf = 0; nf < 4; ++nf) {
        const int u = wn * 64 + nf * 16 + cn;
        orow[u] = fmaxf(acc[mf][nf][r], 0.f);
      }
    }
  }
}

extern "C" void kernel_launch(void* const* d_in, const int* in_sizes, int n_in,
                              void* d_out, int out_size, void* d_ws, size_t ws_size,
                              hipStream_t stream) {
  const float* x = (const float*)d_in[0];   // (16,64,64,64) f32
  const float* w = (const float*)d_in[1];   // (128,64,64,64) f32
  float* out = (float*)d_out;               // (16,64,64,128) f32

  const size_t XB_BYTES = (size_t)16 * 64 * 64 * 64 * 2;      // 8,388,608
  const size_t WB_BYTES = (size_t)64 * 128 * 64 * 64 * 2;     // 67,108,864
  const size_t PB_BYTES = (size_t)16 * 64 * 64 * 128 * 2;     // 16,777,216

  if (ws_size >= XB_BYTES + WB_BYTES + 2 * PB_BYTES) {
    ushort_t* Xb = (ushort_t*)d_ws;
    ushort_t* Wb = (ushort_t*)((char*)d_ws + XB_BYTES);
    ushort_t* P0 = (ushort_t*)((char*)d_ws + XB_BYTES + WB_BYTES);
    ushort_t* P1 = (ushort_t*)((char*)d_ws + XB_BYTES + WB_BYTES + PB_BYTES);
    hipLaunchKernelGGL(conv_x, dim3(1024), dim3(256), 0, stream, x, Xb,
                       (int)(16 * 64 * 64 * 64 / 4));
    hipLaunchKernelGGL(conv_w, dim3(8192), dim3(256), 0, stream, w, Wb);
    hipLaunchKernelGGL(gemm256k, dim3(256), dim3(512), 0, stream, Xb, Wb, P0, P1);
    hipLaunchKernelGGL(add_relu_bf, dim3(4096), dim3(256), 0, stream, P0, P1,
                       out, (int)(16 * 64 * 64 * 128 / 8));
  } else if (ws_size >= XB_BYTES + WB_BYTES) {
    ushort_t* Xb = (ushort_t*)d_ws;
    ushort_t* Wb = (ushort_t*)((char*)d_ws + XB_BYTES);
    hipLaunchKernelGGL(conv_x, dim3(1024), dim3(256), 0, stream, x, Xb,
                       (int)(16 * 64 * 64 * 64 / 4));
    hipLaunchKernelGGL(conv_w, dim3(8192), dim3(256), 0, stream, w, Wb);
    hipLaunchKernelGGL(gemm8, dim3(256), dim3(512), 0, stream, Xb, Wb, out);
  } else {
    hipLaunchKernelGGL(fused_gemm, dim3(512), dim3(256), 0, stream, x, w, out);
  }
}